// Round 9
// baseline (199.285 us; speedup 1.0000x reference)
//
#include <hip/hip_runtime.h>
#include <math.h>

#define NEG_SLOPE 0.2f
#define EPS_DEN 1e-16f

typedef __attribute__((ext_vector_type(8))) short bf16x8;
typedef __attribute__((ext_vector_type(4))) float f32x4;

__device__ inline void split2(float a, short& hi, short& lo) {
    unsigned u = __float_as_uint(a);
    unsigned uh = (u + 0x8000u) & 0xFFFF0000u;
    float fh = __uint_as_float(uh);
    hi = (short)(uh >> 16);
    float r = a - fh;
    lo = (short)((__float_as_uint(r) + 0x8000u) >> 16);
}

__device__ inline unsigned short f2bf(float f) {   // RNE
    unsigned u = __float_as_uint(f);
    return (unsigned short)((u + 0x7FFFu + ((u >> 16) & 1u)) >> 16);
}
__device__ inline float bflo(unsigned u) { return __uint_as_float(u << 16); }
__device__ inline float bfhi(unsigned u) { return __uint_as_float(u & 0xFFFF0000u); }

// ---------------- CSR build ----------------
__global__ void k_count(const int* __restrict__ ei, int E, int Nn, int* counts) {
    int e = blockIdx.x * blockDim.x + threadIdx.x;
    int ET = E + Nn;
    if (e >= ET) return;
    int d = (e < E) ? ei[E + e] : (e - E);
    atomicAdd(&counts[d], 1);
}

__global__ void k_scan(const int* __restrict__ counts, int Nn, int ET, int* __restrict__ row_off) {
    __shared__ int lds[256];
    int t = threadIdx.x;
    int chunk = (Nn + 255) / 256;
    int b0 = t * chunk, b1 = min(Nn, b0 + chunk);
    int s = 0;
    for (int i = b0; i < b1; i++) s += counts[i];
    lds[t] = s;
    __syncthreads();
    if (t == 0) {
        int run = 0;
        for (int i = 0; i < 256; i++) { int v = lds[i]; lds[i] = run; run += v; }
    }
    __syncthreads();
    int run = lds[t];
    for (int i = b0; i < b1; i++) { row_off[i] = run; run += counts[i]; }
    if (t == 0) row_off[Nn] = ET;
}

__global__ void k_scatter(const int* __restrict__ ei, int E, int Nn,
                          const int* __restrict__ row_off, int* cursor, int* __restrict__ col) {
    int e = blockIdx.x * blockDim.x + threadIdx.x;
    int ET = E + Nn;
    if (e >= ET) return;
    int d = (e < E) ? ei[E + e] : (e - E);
    int s = (e < E) ? ei[e] : (e - E);
    int pos = atomicAdd(&cursor[d], 1);
    col[row_off[d] + pos] = s;
}

// ---------------- split conversions ----------------
__global__ void k_split_x(const float* __restrict__ x, short* __restrict__ A,
                          int M, int Mp, int K) {
    int i = blockIdx.x * blockDim.x + threadIdx.x;
    if (i >= Mp * K) return;
    int row = i / K, c = i - row * K;
    float v = (row < M) ? x[(size_t)row * K + c] : 0.f;
    short hi, lo;
    split2(v, hi, lo);
    A[(size_t)row * (2 * K) + c] = hi;
    A[(size_t)row * (2 * K) + K + c] = lo;
}

// W [K,N] f32 -> Bt [N, (1+dup)K] bf16 (transposed; dup=1 writes [hi|hi] for split-A GEMM)
__global__ __launch_bounds__(256) void k_split_wt(const float* __restrict__ W,
                                                  short* __restrict__ Bt, int K, int N, int dup) {
    __shared__ float s[32][33];
    int k0 = blockIdx.x * 32, n0 = blockIdx.y * 32;
    int tx = threadIdx.x & 31, ty = threadIdx.x >> 5;
    for (int r = ty; r < 32; r += 8) s[r][tx] = W[(size_t)(k0 + r) * N + n0 + tx];
    __syncthreads();
    int ldbt = (1 + dup) * K;
    for (int r = ty; r < 32; r += 8) {
        float v = s[tx][r];
        unsigned u = __float_as_uint(v);
        short hi = (short)((u + 0x7FFFu + ((u >> 16) & 1u)) >> 16);
        size_t base = (size_t)(n0 + r) * ldbt + k0 + tx;
        Bt[base] = hi;
        if (dup) Bt[base + K] = hi;
    }
}

// ---------------- MFMA bf16 GEMM, 64x64 tile, BK=32, XCD-grouped, swizzled LDS ----------------
__global__ __launch_bounds__(256) void k_mfma64(const short* __restrict__ A,
                                                const short* __restrict__ B,
                                                unsigned short* __restrict__ C,
                                                int M, int N, int Ktot,
                                                int lda, int ldb) {
    __shared__ short As[64 * 32];
    __shared__ short Bs[64 * 32];
    int t = threadIdx.x;
    int lane = t & 63;
    int wid = t >> 6;

    int nbx = N >> 6;
    int nb = gridDim.x;
    int q = nb >> 3, r = nb & 7;
    int xcd = blockIdx.x & 7, pos = blockIdx.x >> 3;
    int L = (xcd < r ? xcd * (q + 1) : r * (q + 1) + (xcd - r) * q) + pos;
    int bn = (L % nbx) * 64;
    int bm = (L / nbx) * 64;

    int wm = (wid >> 1) * 32, wn = (wid & 1) * 32;
    int fr = lane & 15, kq = lane >> 4;

    int srow = t >> 2, sslot = t & 3;
    int sko = ((sslot ^ ((srow >> 1) & 3)) << 3);

    f32x4 acc[2][2] = {};

    for (int k0 = 0; k0 < Ktot; k0 += 32) {
        {
            const short* sa = A + (size_t)(bm + srow) * lda + k0 + sko;
            const short* sb = B + (size_t)(bn + srow) * ldb + k0 + sko;
            short* da = As + (size_t)(wid << 6) * 8;
            short* db = Bs + (size_t)(wid << 6) * 8;
            __builtin_amdgcn_global_load_lds((const __attribute__((address_space(1))) void*)sa,
                                             (__attribute__((address_space(3))) void*)da, 16, 0, 0);
            __builtin_amdgcn_global_load_lds((const __attribute__((address_space(1))) void*)sb,
                                             (__attribute__((address_space(3))) void*)db, 16, 0, 0);
        }
        __syncthreads();
        bf16x8 af[2], bfv[2];
        #pragma unroll
        for (int i = 0; i < 2; i++) {
            int rowa = wm + i * 16 + fr;
            int rowb = wn + i * 16 + fr;
            af[i]  = *(const bf16x8*)(As + rowa * 32 + ((kq ^ ((rowa >> 1) & 3)) << 3));
            bfv[i] = *(const bf16x8*)(Bs + rowb * 32 + ((kq ^ ((rowb >> 1) & 3)) << 3));
        }
        #pragma unroll
        for (int i = 0; i < 2; i++)
            #pragma unroll
            for (int j = 0; j < 2; j++)
                acc[i][j] = __builtin_amdgcn_mfma_f32_16x16x32_bf16(af[i], bfv[j], acc[i][j], 0, 0, 0);
        __syncthreads();
    }
    #pragma unroll
    for (int i = 0; i < 2; i++) {
        int rbase = bm + wm + i * 16 + kq * 4;
        #pragma unroll
        for (int j = 0; j < 2; j++) {
            int colc = bn + wn + j * 16 + fr;
            #pragma unroll
            for (int rg = 0; rg < 4; rg++) {
                int rr = rbase + rg;
                if (rr < M) C[(size_t)rr * N + colc] = f2bf(acc[i][j][rg]);
            }
        }
    }
}

// ---------------- scores: wave per node, 8-lane head groups ----------------
template<int H, int C>
__global__ __launch_bounds__(256) void k_scores_bf(const unsigned short* __restrict__ h,
                                                   const float* __restrict__ a_src,
                                                   const float* __restrict__ a_dst,
                                                   float* __restrict__ ssrc,
                                                   float* __restrict__ sdst, int Nn) {
    constexpr int D = H * C;
    constexpr int PER = D / 64;      // elems per lane (16 or 8)
    constexpr int GRP = C / PER;     // lanes per head (8)
    int lane = threadIdx.x & 63;
    int n = blockIdx.x * 4 + (threadIdx.x >> 6);
    if (n >= Nn) return;
    const unsigned short* hp = h + (size_t)n * D + lane * PER;
    int cb = lane * PER;
    float as = 0.f, ad = 0.f;
    #pragma unroll
    for (int j0 = 0; j0 < PER; j0 += 8) {
        uint4 u = *(const uint4*)(hp + j0);
        int c = cb + j0;
        as += bflo(u.x) * a_src[c + 0] + bfhi(u.x) * a_src[c + 1]
            + bflo(u.y) * a_src[c + 2] + bfhi(u.y) * a_src[c + 3]
            + bflo(u.z) * a_src[c + 4] + bfhi(u.z) * a_src[c + 5]
            + bflo(u.w) * a_src[c + 6] + bfhi(u.w) * a_src[c + 7];
        ad += bflo(u.x) * a_dst[c + 0] + bfhi(u.x) * a_dst[c + 1]
            + bflo(u.y) * a_dst[c + 2] + bfhi(u.y) * a_dst[c + 3]
            + bflo(u.z) * a_dst[c + 4] + bfhi(u.z) * a_dst[c + 5]
            + bflo(u.w) * a_dst[c + 6] + bfhi(u.w) * a_dst[c + 7];
    }
    #pragma unroll
    for (int off = GRP >> 1; off >= 1; off >>= 1) {
        as += __shfl_xor(as, off);
        ad += __shfl_xor(ad, off);
    }
    if ((lane & (GRP - 1)) == 0) {
        int hh = lane / GRP;
        ssrc[n * H + hh] = as;
        sdst[n * H + hh] = ad;
    }
}

// ---------------- layer-3 GEMM + scores: N=3, K=512, wave per row ----------------
__global__ __launch_bounds__(256) void k_gemm_n3s(const float* __restrict__ A, const float* __restrict__ W,
                                                  const float* __restrict__ as3, const float* __restrict__ ad3,
                                                  float* __restrict__ C3, float* __restrict__ ssrc,
                                                  float* __restrict__ sdst, int M, int K) {
    __shared__ float lw[1536];
    int t = threadIdx.x;
    for (int i = t; i < K * 3; i += 256) lw[i] = W[i];
    __syncthreads();
    int lane = t & 63;
    int n = blockIdx.x * 4 + (t >> 6);
    if (n >= M) return;
    float a0 = 0.f, a1 = 0.f, a2 = 0.f;
    for (int c = lane; c < K; c += 64) {
        float v = A[(size_t)n * K + c];
        a0 += v * lw[c * 3 + 0];
        a1 += v * lw[c * 3 + 1];
        a2 += v * lw[c * 3 + 2];
    }
    #pragma unroll
    for (int off = 32; off > 0; off >>= 1) {
        a0 += __shfl_xor(a0, off);
        a1 += __shfl_xor(a1, off);
        a2 += __shfl_xor(a2, off);
    }
    if (lane == 0) {
        C3[n * 3 + 0] = a0; C3[n * 3 + 1] = a1; C3[n * 3 + 2] = a2;
        ssrc[n] = a0 * as3[0] + a1 * as3[1] + a2 * as3[2];
        sdst[n] = a0 * ad3[0] + a1 * ad3[1] + a2 * ad3[2];
    }
}

// ---------------- aggregation: wave per (node, 512-col slice), no LDS, no barriers ----------------
// CB = D/512 slices per node. Each lane owns 8 contiguous cols (16B loads).
template<int H, int C, int CB, bool ELU, bool BFOUT>
__global__ __launch_bounds__(256) void k_agg_wv(const unsigned short* __restrict__ hsrc,
                                                const float* __restrict__ ssrc,
                                                const float* __restrict__ sdst,
                                                const int* __restrict__ col,
                                                const int* __restrict__ row_off,
                                                const float* __restrict__ bias,
                                                float* __restrict__ out,
                                                unsigned short* __restrict__ osp) {
    constexpr int D = H * C;
    int lane = threadIdx.x & 63;
    int w = blockIdx.x * 4 + (threadIdx.x >> 6);
    if (w >= 10000 * CB) {}   // guarded below via Nn param-free template; actual guard:
    int n, cb;
    if (CB == 2) { n = w >> 1; cb = w & 1; } else { n = w; cb = 0; }
    int col0 = cb * 512 + lane * 8;
    int myhead = col0 / C;
    float sd = sdst[n * H + myhead];
    int beg = row_off[n], end = row_off[n + 1];
    const unsigned short* hbase = hsrc + col0;

    float acc[8] = {0.f, 0.f, 0.f, 0.f, 0.f, 0.f, 0.f, 0.f};
    float den = 0.f;
    #pragma unroll 2
    for (int j = beg; j < end; j++) {
        int cj = col[j];
        float s = ssrc[cj * H + myhead] + sd;
        s = (s >= 0.f) ? s : NEG_SLOPE * s;
        float ex = __expf(s);
        den += ex;
        uint4 u = *(const uint4*)(hbase + (size_t)cj * D);
        acc[0] += ex * bflo(u.x); acc[1] += ex * bfhi(u.x);
        acc[2] += ex * bflo(u.y); acc[3] += ex * bfhi(u.y);
        acc[4] += ex * bflo(u.z); acc[5] += ex * bfhi(u.z);
        acc[6] += ex * bflo(u.w); acc[7] += ex * bfhi(u.w);
    }
    float iv = 1.f / (den + EPS_DEN);
    float vals[8];
    #pragma unroll
    for (int v = 0; v < 8; v++) {
        float val = acc[v] * iv + bias[col0 + v];
        if (ELU) val = (val > 0.f) ? val : (__expf(val) - 1.f);
        vals[v] = val;
    }
    if (BFOUT) {
        uint4 o;
        o.x = (unsigned)f2bf(vals[0]) | ((unsigned)f2bf(vals[1]) << 16);
        o.y = (unsigned)f2bf(vals[2]) | ((unsigned)f2bf(vals[3]) << 16);
        o.z = (unsigned)f2bf(vals[4]) | ((unsigned)f2bf(vals[5]) << 16);
        o.w = (unsigned)f2bf(vals[6]) | ((unsigned)f2bf(vals[7]) << 16);
        *(uint4*)(osp + (size_t)n * D + col0) = o;
    } else {
        *(f32x4*)(out + (size_t)n * D + col0) = *(f32x4*)&vals[0];
        *(f32x4*)(out + (size_t)n * D + col0 + 4) = *(f32x4*)&vals[4];
    }
}

// guard wrapper: pass Nn*CB as limit
template<int H, int C, int CB, bool ELU, bool BFOUT>
__global__ __launch_bounds__(256) void k_agg_wave(const unsigned short* __restrict__ hsrc,
                                                  const float* __restrict__ ssrc,
                                                  const float* __restrict__ sdst,
                                                  const int* __restrict__ col,
                                                  const int* __restrict__ row_off,
                                                  const float* __restrict__ bias,
                                                  float* __restrict__ out,
                                                  unsigned short* __restrict__ osp,
                                                  int nw) {
    constexpr int D = H * C;
    int lane = threadIdx.x & 63;
    int w = blockIdx.x * 4 + (threadIdx.x >> 6);
    if (w >= nw) return;
    int n, cb;
    if (CB == 2) { n = w >> 1; cb = w & 1; } else { n = w; cb = 0; }
    int col0 = cb * 512 + lane * 8;
    int myhead = col0 / C;
    float sd = sdst[n * H + myhead];
    int beg = row_off[n], end = row_off[n + 1];
    const unsigned short* hbase = hsrc + col0;

    float acc[8] = {0.f, 0.f, 0.f, 0.f, 0.f, 0.f, 0.f, 0.f};
    float den = 0.f;
    #pragma unroll 2
    for (int j = beg; j < end; j++) {
        int cj = col[j];
        float s = ssrc[cj * H + myhead] + sd;
        s = (s >= 0.f) ? s : NEG_SLOPE * s;
        float ex = __expf(s);
        den += ex;
        uint4 u = *(const uint4*)(hbase + (size_t)cj * D);
        acc[0] += ex * bflo(u.x); acc[1] += ex * bfhi(u.x);
        acc[2] += ex * bflo(u.y); acc[3] += ex * bfhi(u.y);
        acc[4] += ex * bflo(u.z); acc[5] += ex * bfhi(u.z);
        acc[6] += ex * bflo(u.w); acc[7] += ex * bfhi(u.w);
    }
    float iv = 1.f / (den + EPS_DEN);
    float vals[8];
    #pragma unroll
    for (int v = 0; v < 8; v++) {
        float val = acc[v] * iv + bias[col0 + v];
        if (ELU) val = (val > 0.f) ? val : (__expf(val) - 1.f);
        vals[v] = val;
    }
    if (BFOUT) {
        uint4 o;
        o.x = (unsigned)f2bf(vals[0]) | ((unsigned)f2bf(vals[1]) << 16);
        o.y = (unsigned)f2bf(vals[2]) | ((unsigned)f2bf(vals[3]) << 16);
        o.z = (unsigned)f2bf(vals[4]) | ((unsigned)f2bf(vals[5]) << 16);
        o.w = (unsigned)f2bf(vals[6]) | ((unsigned)f2bf(vals[7]) << 16);
        *(uint4*)(osp + (size_t)n * D + col0) = o;
    } else {
        *(f32x4*)(out + (size_t)n * D + col0) = *(f32x4*)&vals[0];
        *(f32x4*)(out + (size_t)n * D + col0 + 4) = *(f32x4*)&vals[4];
    }
}

// ---------------- fused layer-3: softmax (no shift) + aggregation + log_softmax ----------------
__global__ void k_l3_fused(const float* __restrict__ h3, const float* __restrict__ ssrc,
                           const float* __restrict__ sdst, const int* __restrict__ col,
                           const int* __restrict__ row_off, const float* __restrict__ b3,
                           float* __restrict__ out, int Nn) {
    int n = blockIdx.x * blockDim.x + threadIdx.x;
    if (n >= Nn) return;
    int beg = row_off[n], end = row_off[n + 1];
    float sd = sdst[n];
    float den = 0.f, a0 = 0.f, a1 = 0.f, a2 = 0.f;
    for (int j = beg; j < end; j++) {
        int sI = col[j];
        float s = ssrc[sI] + sd;
        s = (s >= 0.f) ? s : NEG_SLOPE * s;
        float ex = __expf(s);
        den += ex;
        a0 += ex * h3[sI * 3 + 0];
        a1 += ex * h3[sI * 3 + 1];
        a2 += ex * h3[sI * 3 + 2];
    }
    float iv = 1.f / (den + EPS_DEN);
    float v0 = a0 * iv + b3[0], v1 = a1 * iv + b3[1], v2 = a2 * iv + b3[2];
    float m = fmaxf(v0, fmaxf(v1, v2));
    float l = logf(__expf(v0 - m) + __expf(v1 - m) + __expf(v2 - m));
    out[n * 3 + 0] = v0 - m - l;
    out[n * 3 + 1] = v1 - m - l;
    out[n * 3 + 2] = v2 - m - l;
}

extern "C" void kernel_launch(void* const* d_in, const int* in_sizes, int n_in,
                              void* d_out, int out_size, void* d_ws, size_t ws_size,
                              hipStream_t stream) {
    (void)n_in; (void)out_size; (void)ws_size;
    const float* x   = (const float*)d_in[0];
    const int*   ei  = (const int*)d_in[1];
    const float* W1  = (const float*)d_in[2];
    const float* as1 = (const float*)d_in[3];
    const float* ad1 = (const float*)d_in[4];
    const float* b1  = (const float*)d_in[5];
    const float* W2  = (const float*)d_in[6];
    const float* as2 = (const float*)d_in[7];
    const float* ad2 = (const float*)d_in[8];
    const float* b2  = (const float*)d_in[9];
    const float* W3  = (const float*)d_in[10];
    const float* as3 = (const float*)d_in[11];
    const float* ad3 = (const float*)d_in[12];
    const float* b3  = (const float*)d_in[13];
    float* out = (float*)d_out;

    const int Nn = in_sizes[0] / 64;   // 10000
    const int E  = in_sizes[1] / 2;    // 160000
    const int ET = E + Nn;
    const int Mp = ((Nn + 127) / 128) * 128;   // 10112

    char* ws = (char*)d_ws;
    size_t off = 0;
    auto alloc = [&](size_t bytes) -> void* {
        void* p = ws + off;
        off = (off + bytes + 255) & ~(size_t)255;
        return p;
    };
    unsigned short* hbuf = (unsigned short*)alloc((size_t)Mp * 1024 * 2);
    void*  big  = alloc((size_t)Mp * 1024 * 2 + 65536);
    unsigned short* A2 = (unsigned short*)big;
    float* obuf = (float*)big;
    float* h3   = (float*)alloc((size_t)Nn * 3 * 4);
    short* A1   = (short*)alloc((size_t)Mp * 128 * 2);
    short* B1t  = (short*)alloc((size_t)1024 * 128 * 2);
    short* B2t  = (short*)alloc((size_t)512 * 1024 * 2);
    float* ssrc = (float*)alloc((size_t)Nn * 8 * 4);
    float* sdst = (float*)alloc((size_t)Nn * 8 * 4);
    int* counts = (int*)alloc((size_t)Nn * 2 * 4);
    int* cursor = counts + Nn;
    int* row_off= (int*)alloc((size_t)(Nn + 1) * 4);
    int* colb   = (int*)alloc((size_t)ET * 4);

    hipMemsetAsync(counts, 0, (size_t)Nn * 2 * 4, stream);

    int etb = (ET + 255) / 256;
    k_count<<<etb, 256, 0, stream>>>(ei, E, Nn, counts);
    k_scan<<<1, 256, 0, stream>>>(counts, Nn, ET, row_off);
    k_scatter<<<etb, 256, 0, stream>>>(ei, E, Nn, row_off, cursor, colb);

    k_split_x<<<(Mp * 64 + 255) / 256, 256, 0, stream>>>(x, A1, Nn, Mp, 64);
    k_split_wt<<<dim3(64 / 32, 1024 / 32), 256, 0, stream>>>(W1, B1t, 64, 1024, 1);
    k_split_wt<<<dim3(1024 / 32, 512 / 32), 256, 0, stream>>>(W2, B2t, 1024, 512, 0);

    // ---- layer 1: 64 -> 8x128 concat (A split 2-term) ----
    {
        int nb = (1024 / 64) * (Mp / 64);
        k_mfma64<<<nb, 256, 0, stream>>>(A1, B1t, hbuf, Nn, 1024, 128, 128, 128);
        k_scores_bf<8, 128><<<(Nn + 3) / 4, 256, 0, stream>>>(hbuf, as1, ad1, ssrc, sdst, Nn);
        int nw = Nn * 2;
        k_agg_wave<8, 128, 2, true, true><<<(nw + 3) / 4, 256, 0, stream>>>(hbuf, ssrc, sdst, colb, row_off, b1, nullptr, A2, nw);
    }
    // ---- layer 2: 1024 -> 8x64 concat (plain bf16 GEMM) ----
    {
        int nb = (512 / 64) * (Mp / 64);
        k_mfma64<<<nb, 256, 0, stream>>>((const short*)A2, B2t, hbuf, Nn, 512, 1024, 1024, 1024);
        k_scores_bf<8, 64><<<(Nn + 3) / 4, 256, 0, stream>>>(hbuf, as2, ad2, ssrc, sdst, Nn);
        int nw = Nn;
        k_agg_wave<8, 64, 1, true, false><<<(nw + 3) / 4, 256, 0, stream>>>(hbuf, ssrc, sdst, colb, row_off, b2, obuf, nullptr, nw);
    }
    // ---- layer 3: 512 -> 1x3, mean + log_softmax (fused) ----
    {
        k_gemm_n3s<<<(Nn + 3) / 4, 256, 0, stream>>>(obuf, W3, as3, ad3, h3, ssrc, sdst, Nn, 512);
        k_l3_fused<<<(Nn + 255) / 256, 256, 0, stream>>>(h3, ssrc, sdst, colb, row_off, b3, out, Nn);
    }
}

// Round 10
// 190.325 us; speedup vs baseline: 1.0471x; 1.0471x over previous
//
#include <hip/hip_runtime.h>
#include <math.h>

#define NEG_SLOPE 0.2f
#define EPS_DEN 1e-16f

typedef __attribute__((ext_vector_type(8))) short bf16x8;
typedef __attribute__((ext_vector_type(4))) float f32x4;

__device__ inline void split2(float a, short& hi, short& lo) {
    unsigned u = __float_as_uint(a);
    unsigned uh = (u + 0x8000u) & 0xFFFF0000u;
    float fh = __uint_as_float(uh);
    hi = (short)(uh >> 16);
    float r = a - fh;
    lo = (short)((__float_as_uint(r) + 0x8000u) >> 16);
}

__device__ inline unsigned short f2bf(float f) {   // RNE
    unsigned u = __float_as_uint(f);
    return (unsigned short)((u + 0x7FFFu + ((u >> 16) & 1u)) >> 16);
}
__device__ inline float bflo(unsigned u) { return __uint_as_float(u << 16); }
__device__ inline float bfhi(unsigned u) { return __uint_as_float(u & 0xFFFF0000u); }

// ---------------- CSR build ----------------
__global__ void k_count(const int* __restrict__ ei, int E, int Nn, int* counts) {
    int e = blockIdx.x * blockDim.x + threadIdx.x;
    int ET = E + Nn;
    if (e >= ET) return;
    int d = (e < E) ? ei[E + e] : (e - E);
    atomicAdd(&counts[d], 1);
}

__global__ void k_scan(const int* __restrict__ counts, int Nn, int ET, int* __restrict__ row_off) {
    __shared__ int lds[256];
    int t = threadIdx.x;
    int chunk = (Nn + 255) / 256;
    int b0 = t * chunk, b1 = min(Nn, b0 + chunk);
    int s = 0;
    for (int i = b0; i < b1; i++) s += counts[i];
    lds[t] = s;
    __syncthreads();
    #pragma unroll
    for (int d = 1; d < 256; d <<= 1) {
        int v = (t >= d) ? lds[t - d] : 0;
        __syncthreads();
        lds[t] += v;
        __syncthreads();
    }
    int run = (t == 0) ? 0 : lds[t - 1];
    for (int i = b0; i < b1; i++) { row_off[i] = run; run += counts[i]; }
    if (t == 0) row_off[Nn] = ET;
}

__global__ void k_scatter(const int* __restrict__ ei, int E, int Nn,
                          const int* __restrict__ row_off, int* cursor, int* __restrict__ col) {
    int e = blockIdx.x * blockDim.x + threadIdx.x;
    int ET = E + Nn;
    if (e >= ET) return;
    int d = (e < E) ? ei[E + e] : (e - E);
    int s = (e < E) ? ei[e] : (e - E);
    int pos = atomicAdd(&cursor[d], 1);
    col[row_off[d] + pos] = s;
}

// ---------------- split conversions ----------------
__global__ void k_split_x(const float* __restrict__ x, short* __restrict__ A,
                          int M, int Mp, int K) {
    int i = blockIdx.x * blockDim.x + threadIdx.x;
    if (i >= Mp * K) return;
    int row = i / K, c = i - row * K;
    float v = (row < M) ? x[(size_t)row * K + c] : 0.f;
    short hi, lo;
    split2(v, hi, lo);
    A[(size_t)row * (2 * K) + c] = hi;
    A[(size_t)row * (2 * K) + K + c] = lo;
}

__global__ __launch_bounds__(256) void k_split_wt(const float* __restrict__ W,
                                                  short* __restrict__ Bt, int K, int N, int dup) {
    __shared__ float s[32][33];
    int k0 = blockIdx.x * 32, n0 = blockIdx.y * 32;
    int tx = threadIdx.x & 31, ty = threadIdx.x >> 5;
    for (int r = ty; r < 32; r += 8) s[r][tx] = W[(size_t)(k0 + r) * N + n0 + tx];
    __syncthreads();
    int ldbt = (1 + dup) * K;
    for (int r = ty; r < 32; r += 8) {
        float v = s[tx][r];
        unsigned u = __float_as_uint(v);
        short hi = (short)((u + 0x7FFFu + ((u >> 16) & 1u)) >> 16);
        size_t base = (size_t)(n0 + r) * ldbt + k0 + tx;
        Bt[base] = hi;
        if (dup) Bt[base + K] = hi;
    }
}

// ---------------- MFMA bf16 GEMM, 64x64 tile, BK=32, XCD-grouped, swizzled LDS ----------------
// FUSESC (layer 2, C=64): each 64-col block = exactly one head -> compute complete
// ssrc/sdst for its 64 rows in the epilogue (shfl + LDS cross-wave reduce, direct stores).
template<bool FUSESC>
__global__ __launch_bounds__(256) void k_mfma64(const short* __restrict__ A,
                                                const short* __restrict__ B,
                                                unsigned short* __restrict__ C,
                                                const float* __restrict__ a_src,
                                                const float* __restrict__ a_dst,
                                                float* __restrict__ ssrc,
                                                float* __restrict__ sdst,
                                                int M, int N, int Ktot,
                                                int lda, int ldb) {
    __shared__ short As[64 * 32];
    __shared__ short Bs[64 * 32];
    __shared__ float sred[4][64][2];
    int t = threadIdx.x;
    int lane = t & 63;
    int wid = t >> 6;

    int nbx = N >> 6;
    int nb = gridDim.x;
    int q = nb >> 3, r = nb & 7;
    int xcd = blockIdx.x & 7, pos = blockIdx.x >> 3;
    int L = (xcd < r ? xcd * (q + 1) : r * (q + 1) + (xcd - r) * q) + pos;
    int bn = (L % nbx) * 64;
    int bm = (L / nbx) * 64;

    int wm = (wid >> 1) * 32, wn = (wid & 1) * 32;
    int fr = lane & 15, kq = lane >> 4;

    int srow = t >> 2, sslot = t & 3;
    int sko = ((sslot ^ ((srow >> 1) & 3)) << 3);

    f32x4 acc[2][2] = {};

    for (int k0 = 0; k0 < Ktot; k0 += 32) {
        {
            const short* sa = A + (size_t)(bm + srow) * lda + k0 + sko;
            const short* sb = B + (size_t)(bn + srow) * ldb + k0 + sko;
            short* da = As + (size_t)(wid << 6) * 8;
            short* db = Bs + (size_t)(wid << 6) * 8;
            __builtin_amdgcn_global_load_lds((const __attribute__((address_space(1))) void*)sa,
                                             (__attribute__((address_space(3))) void*)da, 16, 0, 0);
            __builtin_amdgcn_global_load_lds((const __attribute__((address_space(1))) void*)sb,
                                             (__attribute__((address_space(3))) void*)db, 16, 0, 0);
        }
        __syncthreads();
        bf16x8 af[2], bfv[2];
        #pragma unroll
        for (int i = 0; i < 2; i++) {
            int rowa = wm + i * 16 + fr;
            int rowb = wn + i * 16 + fr;
            af[i]  = *(const bf16x8*)(As + rowa * 32 + ((kq ^ ((rowa >> 1) & 3)) << 3));
            bfv[i] = *(const bf16x8*)(Bs + rowb * 32 + ((kq ^ ((rowb >> 1) & 3)) << 3));
        }
        #pragma unroll
        for (int i = 0; i < 2; i++)
            #pragma unroll
            for (int j = 0; j < 2; j++)
                acc[i][j] = __builtin_amdgcn_mfma_f32_16x16x32_bf16(af[i], bfv[j], acc[i][j], 0, 0, 0);
        __syncthreads();
    }
    #pragma unroll
    for (int i = 0; i < 2; i++) {
        int rbase = bm + wm + i * 16 + kq * 4;
        #pragma unroll
        for (int j = 0; j < 2; j++) {
            int colc = bn + wn + j * 16 + fr;
            #pragma unroll
            for (int rg = 0; rg < 4; rg++) {
                int rr = rbase + rg;
                if (rr < M) C[(size_t)rr * N + colc] = f2bf(acc[i][j][rg]);
            }
        }
    }
    if (FUSESC) {
        // per-lane partials over its 2 cols, for its 8 rows
        float asv[2], adv[2];
        #pragma unroll
        for (int j = 0; j < 2; j++) {
            int colc = bn + wn + j * 16 + fr;     // a_src flat [N], heads contiguous
            asv[j] = a_src[colc];
            adv[j] = a_dst[colc];
        }
        float ps[8], pd[8];
        #pragma unroll
        for (int i = 0; i < 2; i++)
            #pragma unroll
            for (int rg = 0; rg < 4; rg++) {
                int k8 = i * 4 + rg;
                ps[k8] = acc[i][0][rg] * asv[0] + acc[i][1][rg] * asv[1];
                pd[k8] = acc[i][0][rg] * adv[0] + acc[i][1][rg] * adv[1];
            }
        #pragma unroll
        for (int k8 = 0; k8 < 8; k8++) {
            #pragma unroll
            for (int off = 1; off < 16; off <<= 1) {
                ps[k8] += __shfl_xor(ps[k8], off);
                pd[k8] += __shfl_xor(pd[k8], off);
            }
        }
        if (fr == 0) {
            #pragma unroll
            for (int i = 0; i < 2; i++)
                #pragma unroll
                for (int rg = 0; rg < 4; rg++) {
                    int rl = wm + i * 16 + kq * 4 + rg;
                    sred[wid][rl][0] = ps[i * 4 + rg];
                    sred[wid][rl][1] = pd[i * 4 + rg];
                }
        }
        __syncthreads();
        if ((wid & 1) == 0 && fr == 0) {
            int hh = bn >> 6;
            #pragma unroll
            for (int i = 0; i < 2; i++)
                #pragma unroll
                for (int rg = 0; rg < 4; rg++) {
                    int rl = wm + i * 16 + kq * 4 + rg;
                    int rr = bm + rl;
                    if (rr < M) {
                        ssrc[rr * 8 + hh] = sred[wid][rl][0] + sred[wid | 1][rl][0];
                        sdst[rr * 8 + hh] = sred[wid][rl][1] + sred[wid | 1][rl][1];
                    }
                }
        }
    }
}

// ---------------- scores (layer 1): wave per node, 8-lane head groups ----------------
template<int H, int C>
__global__ __launch_bounds__(256) void k_scores_bf(const unsigned short* __restrict__ h,
                                                   const float* __restrict__ a_src,
                                                   const float* __restrict__ a_dst,
                                                   float* __restrict__ ssrc,
                                                   float* __restrict__ sdst, int Nn) {
    constexpr int D = H * C;
    constexpr int PER = D / 64;
    constexpr int GRP = C / PER;
    int lane = threadIdx.x & 63;
    int n = blockIdx.x * 4 + (threadIdx.x >> 6);
    if (n >= Nn) return;
    const unsigned short* hp = h + (size_t)n * D + lane * PER;
    int cb = lane * PER;
    float as = 0.f, ad = 0.f;
    #pragma unroll
    for (int j0 = 0; j0 < PER; j0 += 8) {
        uint4 u = *(const uint4*)(hp + j0);
        int c = cb + j0;
        as += bflo(u.x) * a_src[c + 0] + bfhi(u.x) * a_src[c + 1]
            + bflo(u.y) * a_src[c + 2] + bfhi(u.y) * a_src[c + 3]
            + bflo(u.z) * a_src[c + 4] + bfhi(u.z) * a_src[c + 5]
            + bflo(u.w) * a_src[c + 6] + bfhi(u.w) * a_src[c + 7];
        ad += bflo(u.x) * a_dst[c + 0] + bfhi(u.x) * a_dst[c + 1]
            + bflo(u.y) * a_dst[c + 2] + bfhi(u.y) * a_dst[c + 3]
            + bflo(u.z) * a_dst[c + 4] + bfhi(u.z) * a_dst[c + 5]
            + bflo(u.w) * a_dst[c + 6] + bfhi(u.w) * a_dst[c + 7];
    }
    #pragma unroll
    for (int off = GRP >> 1; off >= 1; off >>= 1) {
        as += __shfl_xor(as, off);
        ad += __shfl_xor(ad, off);
    }
    if ((lane & (GRP - 1)) == 0) {
        int hh = lane / GRP;
        ssrc[n * H + hh] = as;
        sdst[n * H + hh] = ad;
    }
}

// ---------------- layer-1 aggregation: wave per (node, 512-col slice) ----------------
template<int H, int C, int CB, bool ELU, bool BFOUT>
__global__ __launch_bounds__(256) void k_agg_wave(const unsigned short* __restrict__ hsrc,
                                                  const float* __restrict__ ssrc,
                                                  const float* __restrict__ sdst,
                                                  const int* __restrict__ col,
                                                  const int* __restrict__ row_off,
                                                  const float* __restrict__ bias,
                                                  float* __restrict__ out,
                                                  unsigned short* __restrict__ osp,
                                                  int nw) {
    constexpr int D = H * C;
    int lane = threadIdx.x & 63;
    int w = blockIdx.x * 4 + (threadIdx.x >> 6);
    if (w >= nw) return;
    int n, cb;
    if (CB == 2) { n = w >> 1; cb = w & 1; } else { n = w; cb = 0; }
    int col0 = cb * 512 + lane * 8;
    int myhead = col0 / C;
    float sd = sdst[n * H + myhead];
    int beg = row_off[n], end = row_off[n + 1];
    const unsigned short* hbase = hsrc + col0;

    float acc[8] = {0.f, 0.f, 0.f, 0.f, 0.f, 0.f, 0.f, 0.f};
    float den = 0.f;
    #pragma unroll 2
    for (int j = beg; j < end; j++) {
        int cj = col[j];
        float s = ssrc[cj * H + myhead] + sd;
        s = (s >= 0.f) ? s : NEG_SLOPE * s;
        float ex = __expf(s);
        den += ex;
        uint4 u = *(const uint4*)(hbase + (size_t)cj * D);
        acc[0] += ex * bflo(u.x); acc[1] += ex * bfhi(u.x);
        acc[2] += ex * bflo(u.y); acc[3] += ex * bfhi(u.y);
        acc[4] += ex * bflo(u.z); acc[5] += ex * bfhi(u.z);
        acc[6] += ex * bflo(u.w); acc[7] += ex * bfhi(u.w);
    }
    float iv = 1.f / (den + EPS_DEN);
    float vals[8];
    #pragma unroll
    for (int v = 0; v < 8; v++) {
        float val = acc[v] * iv + bias[col0 + v];
        if (ELU) val = (val > 0.f) ? val : (__expf(val) - 1.f);
        vals[v] = val;
    }
    if (BFOUT) {
        uint4 o;
        o.x = (unsigned)f2bf(vals[0]) | ((unsigned)f2bf(vals[1]) << 16);
        o.y = (unsigned)f2bf(vals[2]) | ((unsigned)f2bf(vals[3]) << 16);
        o.z = (unsigned)f2bf(vals[4]) | ((unsigned)f2bf(vals[5]) << 16);
        o.w = (unsigned)f2bf(vals[6]) | ((unsigned)f2bf(vals[7]) << 16);
        *(uint4*)(osp + (size_t)n * D + col0) = o;
    } else {
        *(f32x4*)(out + (size_t)n * D + col0) = *(f32x4*)&vals[0];
        *(f32x4*)(out + (size_t)n * D + col0 + 4) = *(f32x4*)&vals[4];
    }
}

// ---------------- layer-2 aggregation + ELU + W3-GEMM + layer-3 scores, wave per node ----------------
__global__ __launch_bounds__(256) void k_agg2_l3(const unsigned short* __restrict__ hsrc,
                                                 const float* __restrict__ ssrc,
                                                 const float* __restrict__ sdst,
                                                 const int* __restrict__ col,
                                                 const int* __restrict__ row_off,
                                                 const float* __restrict__ bias,
                                                 const float* __restrict__ W3,
                                                 const float* __restrict__ as3,
                                                 const float* __restrict__ ad3,
                                                 float* __restrict__ h3,
                                                 float* __restrict__ ssrc3,
                                                 float* __restrict__ sdst3,
                                                 int Nn) {
    constexpr int D = 512;
    int lane = threadIdx.x & 63;
    int n = blockIdx.x * 4 + (threadIdx.x >> 6);
    if (n >= Nn) return;
    int col0 = lane * 8;
    int myhead = lane >> 3;              // C=64: 8 lanes per head
    float sd = sdst[n * 8 + myhead];
    int beg = row_off[n], end = row_off[n + 1];
    const unsigned short* hbase = hsrc + col0;

    float acc[8] = {0.f, 0.f, 0.f, 0.f, 0.f, 0.f, 0.f, 0.f};
    float den = 0.f;
    #pragma unroll 2
    for (int j = beg; j < end; j++) {
        int cj = col[j];
        float s = ssrc[cj * 8 + myhead] + sd;
        s = (s >= 0.f) ? s : NEG_SLOPE * s;
        float ex = __expf(s);
        den += ex;
        uint4 u = *(const uint4*)(hbase + (size_t)cj * D);
        acc[0] += ex * bflo(u.x); acc[1] += ex * bfhi(u.x);
        acc[2] += ex * bflo(u.y); acc[3] += ex * bfhi(u.y);
        acc[4] += ex * bflo(u.z); acc[5] += ex * bfhi(u.z);
        acc[6] += ex * bflo(u.w); acc[7] += ex * bfhi(u.w);
    }
    float iv = 1.f / (den + EPS_DEN);
    float t0 = 0.f, t1 = 0.f, t2 = 0.f;
    #pragma unroll
    for (int v = 0; v < 8; v++) {
        float val = acc[v] * iv + bias[col0 + v];
        val = (val > 0.f) ? val : (__expf(val) - 1.f);    // ELU
        const float* wp = W3 + (size_t)(col0 + v) * 3;
        t0 += val * wp[0];
        t1 += val * wp[1];
        t2 += val * wp[2];
    }
    #pragma unroll
    for (int off = 32; off >= 1; off >>= 1) {
        t0 += __shfl_xor(t0, off);
        t1 += __shfl_xor(t1, off);
        t2 += __shfl_xor(t2, off);
    }
    if (lane == 0) {
        h3[n * 3 + 0] = t0; h3[n * 3 + 1] = t1; h3[n * 3 + 2] = t2;
        ssrc3[n] = t0 * as3[0] + t1 * as3[1] + t2 * as3[2];
        sdst3[n] = t0 * ad3[0] + t1 * ad3[1] + t2 * ad3[2];
    }
}

// ---------------- fused layer-3: softmax (no shift) + aggregation + log_softmax ----------------
__global__ void k_l3_fused(const float* __restrict__ h3, const float* __restrict__ ssrc,
                           const float* __restrict__ sdst, const int* __restrict__ col,
                           const int* __restrict__ row_off, const float* __restrict__ b3,
                           float* __restrict__ out, int Nn) {
    int n = blockIdx.x * blockDim.x + threadIdx.x;
    if (n >= Nn) return;
    int beg = row_off[n], end = row_off[n + 1];
    float sd = sdst[n];
    float den = 0.f, a0 = 0.f, a1 = 0.f, a2 = 0.f;
    for (int j = beg; j < end; j++) {
        int sI = col[j];
        float s = ssrc[sI] + sd;
        s = (s >= 0.f) ? s : NEG_SLOPE * s;
        float ex = __expf(s);
        den += ex;
        a0 += ex * h3[sI * 3 + 0];
        a1 += ex * h3[sI * 3 + 1];
        a2 += ex * h3[sI * 3 + 2];
    }
    float iv = 1.f / (den + EPS_DEN);
    float v0 = a0 * iv + b3[0], v1 = a1 * iv + b3[1], v2 = a2 * iv + b3[2];
    float m = fmaxf(v0, fmaxf(v1, v2));
    float l = logf(__expf(v0 - m) + __expf(v1 - m) + __expf(v2 - m));
    out[n * 3 + 0] = v0 - m - l;
    out[n * 3 + 1] = v1 - m - l;
    out[n * 3 + 2] = v2 - m - l;
}

extern "C" void kernel_launch(void* const* d_in, const int* in_sizes, int n_in,
                              void* d_out, int out_size, void* d_ws, size_t ws_size,
                              hipStream_t stream) {
    (void)n_in; (void)out_size; (void)ws_size;
    const float* x   = (const float*)d_in[0];
    const int*   ei  = (const int*)d_in[1];
    const float* W1  = (const float*)d_in[2];
    const float* as1 = (const float*)d_in[3];
    const float* ad1 = (const float*)d_in[4];
    const float* b1  = (const float*)d_in[5];
    const float* W2  = (const float*)d_in[6];
    const float* as2 = (const float*)d_in[7];
    const float* ad2 = (const float*)d_in[8];
    const float* b2  = (const float*)d_in[9];
    const float* W3  = (const float*)d_in[10];
    const float* as3 = (const float*)d_in[11];
    const float* ad3 = (const float*)d_in[12];
    const float* b3  = (const float*)d_in[13];
    float* out = (float*)d_out;

    const int Nn = in_sizes[0] / 64;   // 10000
    const int E  = in_sizes[1] / 2;    // 160000
    const int ET = E + Nn;
    const int Mp = ((Nn + 127) / 128) * 128;   // 10112

    char* ws = (char*)d_ws;
    size_t off = 0;
    auto alloc = [&](size_t bytes) -> void* {
        void* p = ws + off;
        off = (off + bytes + 255) & ~(size_t)255;
        return p;
    };
    unsigned short* hbuf = (unsigned short*)alloc((size_t)Mp * 1024 * 2);
    unsigned short* A2   = (unsigned short*)alloc((size_t)Mp * 1024 * 2);
    float* h3   = (float*)alloc((size_t)Nn * 3 * 4);
    short* A1   = (short*)alloc((size_t)Mp * 128 * 2);
    short* B1t  = (short*)alloc((size_t)1024 * 128 * 2);
    short* B2t  = (short*)alloc((size_t)512 * 1024 * 2);
    float* ssrc = (float*)alloc((size_t)Nn * 8 * 4);
    float* sdst = (float*)alloc((size_t)Nn * 8 * 4);
    float* ssrcB= (float*)alloc((size_t)Nn * 8 * 4);
    float* sdstB= (float*)alloc((size_t)Nn * 8 * 4);
    float* ssrc3= (float*)alloc((size_t)Nn * 4);
    float* sdst3= (float*)alloc((size_t)Nn * 4);
    int* counts = (int*)alloc((size_t)Nn * 2 * 4);
    int* cursor = counts + Nn;
    int* row_off= (int*)alloc((size_t)(Nn + 1) * 4);
    int* colb   = (int*)alloc((size_t)ET * 4);

    hipMemsetAsync(counts, 0, (size_t)Nn * 2 * 4, stream);

    int etb = (ET + 255) / 256;
    k_count<<<etb, 256, 0, stream>>>(ei, E, Nn, counts);
    k_scan<<<1, 256, 0, stream>>>(counts, Nn, ET, row_off);
    k_scatter<<<etb, 256, 0, stream>>>(ei, E, Nn, row_off, cursor, colb);

    k_split_x<<<(Mp * 64 + 255) / 256, 256, 0, stream>>>(x, A1, Nn, Mp, 64);
    k_split_wt<<<dim3(64 / 32, 1024 / 32), 256, 0, stream>>>(W1, B1t, 64, 1024, 1);
    k_split_wt<<<dim3(1024 / 32, 512 / 32), 256, 0, stream>>>(W2, B2t, 1024, 512, 0);

    // ---- layer 1: 64 -> 8x128 concat (A split 2-term) ----
    {
        int nb = (1024 / 64) * (Mp / 64);
        k_mfma64<false><<<nb, 256, 0, stream>>>(A1, B1t, hbuf, nullptr, nullptr, nullptr, nullptr,
                                                Nn, 1024, 128, 128, 128);
        k_scores_bf<8, 128><<<(Nn + 3) / 4, 256, 0, stream>>>(hbuf, as1, ad1, ssrc, sdst, Nn);
        int nw = Nn * 2;
        k_agg_wave<8, 128, 2, true, true><<<(nw + 3) / 4, 256, 0, stream>>>(
            hbuf, ssrc, sdst, colb, row_off, b1, nullptr, A2, nw);
    }
    // ---- layer 2: 1024 -> 8x64 concat (plain bf16 GEMM, scores fused atomic-free) ----
    {
        int nb = (512 / 64) * (Mp / 64);
        k_mfma64<true><<<nb, 256, 0, stream>>>((const short*)A2, B2t, hbuf, as2, ad2, ssrcB, sdstB,
                                               Nn, 512, 1024, 1024, 1024);
        k_agg2_l3<<<(Nn + 3) / 4, 256, 0, stream>>>(hbuf, ssrcB, sdstB, colb, row_off, b2,
                                                    W3, as3, ad3, h3, ssrc3, sdst3, Nn);
    }
    // ---- layer 3: segment softmax + aggregate + log_softmax ----
    k_l3_fused<<<(Nn + 255) / 256, 256, 0, stream>>>(h3, ssrc3, sdst3, colb, row_off, b3, out, Nn);
}

// Round 11
// 182.282 us; speedup vs baseline: 1.0933x; 1.0441x over previous
//
#include <hip/hip_runtime.h>
#include <math.h>

#define NEG_SLOPE 0.2f
#define EPS_DEN 1e-16f

typedef __attribute__((ext_vector_type(8))) short bf16x8;
typedef __attribute__((ext_vector_type(4))) float f32x4;

__device__ inline void split2(float a, short& hi, short& lo) {
    unsigned u = __float_as_uint(a);
    unsigned uh = (u + 0x8000u) & 0xFFFF0000u;
    float fh = __uint_as_float(uh);
    hi = (short)(uh >> 16);
    float r = a - fh;
    lo = (short)((__float_as_uint(r) + 0x8000u) >> 16);
}

__device__ inline unsigned short f2bf(float f) {   // RNE
    unsigned u = __float_as_uint(f);
    return (unsigned short)((u + 0x7FFFu + ((u >> 16) & 1u)) >> 16);
}
__device__ inline float bflo(unsigned u) { return __uint_as_float(u << 16); }
__device__ inline float bfhi(unsigned u) { return __uint_as_float(u & 0xFFFF0000u); }

// ---------------- fused preprocessing: edge count | x split | W1 split | W2 split ----------------
__global__ __launch_bounds__(256) void k_pre(const int* __restrict__ ei, int E, int Nn,
                                             int* __restrict__ counts,
                                             const float* __restrict__ x, short* __restrict__ A1, int Mp,
                                             const float* __restrict__ W1, short* __restrict__ B1t,
                                             const float* __restrict__ W2, short* __restrict__ B2t) {
    __shared__ float s[32][33];
    int t = threadIdx.x;
    int b = blockIdx.x;
    int ET = E + Nn;
    int etb = (ET + 255) / 256;
    int xb = (Mp * 64 + 255) / 256;
    if (b < etb) {
        int e = b * 256 + t;
        if (e < ET) {
            int d = (e < E) ? ei[E + e] : (e - E);
            atomicAdd(&counts[d], 1);
        }
        return;
    }
    b -= etb;
    if (b < xb) {
        int i = b * 256 + t;
        if (i < Mp * 64) {
            int row = i >> 6, c = i & 63;
            float v = (row < Nn) ? x[(size_t)row * 64 + c] : 0.f;
            short hi, lo;
            split2(v, hi, lo);
            A1[(size_t)row * 128 + c] = hi;
            A1[(size_t)row * 128 + 64 + c] = lo;
        }
        return;
    }
    b -= xb;
    const float* W; short* Bt; int K, N, dup, kb, nb;
    if (b < 64) {               // W1: 64x1024, dup=1 -> 2 x 32 tiles
        W = W1; Bt = B1t; K = 64; N = 1024; dup = 1;
        kb = b & 1; nb = b >> 1;
    } else {                    // W2: 1024x512, dup=0 -> 32 x 16 tiles
        b -= 64;
        W = W2; Bt = B2t; K = 1024; N = 512; dup = 0;
        kb = b & 31; nb = b >> 5;
    }
    int k0 = kb * 32, n0 = nb * 32;
    int tx = t & 31, ty = t >> 5;
    for (int r = ty; r < 32; r += 8) s[r][tx] = W[(size_t)(k0 + r) * N + n0 + tx];
    __syncthreads();
    int ldbt = (1 + dup) * K;
    for (int r = ty; r < 32; r += 8) {
        float v = s[tx][r];
        unsigned u = __float_as_uint(v);
        short hi = (short)((u + 0x7FFFu + ((u >> 16) & 1u)) >> 16);
        size_t base = (size_t)(n0 + r) * ldbt + k0 + tx;
        Bt[base] = hi;
        if (dup) Bt[base + K] = hi;
    }
}

// ---------------- CSR scan / scatter ----------------
__global__ void k_scan(const int* __restrict__ counts, int Nn, int ET, int* __restrict__ row_off) {
    __shared__ int lds[256];
    int t = threadIdx.x;
    int chunk = (Nn + 255) / 256;
    int b0 = t * chunk, b1 = min(Nn, b0 + chunk);
    int s = 0;
    for (int i = b0; i < b1; i++) s += counts[i];
    lds[t] = s;
    __syncthreads();
    #pragma unroll
    for (int d = 1; d < 256; d <<= 1) {
        int v = (t >= d) ? lds[t - d] : 0;
        __syncthreads();
        lds[t] += v;
        __syncthreads();
    }
    int run = (t == 0) ? 0 : lds[t - 1];
    for (int i = b0; i < b1; i++) { row_off[i] = run; run += counts[i]; }
    if (t == 0) row_off[Nn] = ET;
}

__global__ void k_scatter(const int* __restrict__ ei, int E, int Nn,
                          const int* __restrict__ row_off, int* cursor, int* __restrict__ col) {
    int e = blockIdx.x * blockDim.x + threadIdx.x;
    int ET = E + Nn;
    if (e >= ET) return;
    int d = (e < E) ? ei[E + e] : (e - E);
    int s = (e < E) ? ei[e] : (e - E);
    int pos = atomicAdd(&cursor[d], 1);
    col[row_off[d] + pos] = s;
}

// ---------------- GEMM1: 64x128 tile, BK=32, fused layer-1 scores (one head/block) ----------------
__global__ __launch_bounds__(256) void k_mfma_w(const short* __restrict__ A,
                                                const short* __restrict__ B,
                                                unsigned short* __restrict__ C,
                                                const float* __restrict__ a_src,
                                                const float* __restrict__ a_dst,
                                                float* __restrict__ ssrc,
                                                float* __restrict__ sdst,
                                                int M, int N, int Ktot,
                                                int lda, int ldb) {
    __shared__ short As[64 * 32];
    __shared__ short Bs[128 * 32];
    __shared__ float sred[4][64][2];
    int t = threadIdx.x;
    int lane = t & 63;
    int wid = t >> 6;

    int nbx = N >> 7;
    int nb = gridDim.x;
    int q = nb >> 3, r = nb & 7;
    int xcd = blockIdx.x & 7, pos = blockIdx.x >> 3;
    int L = (xcd < r ? xcd * (q + 1) : r * (q + 1) + (xcd - r) * q) + pos;
    int bn = (L % nbx) * 128;
    int bm = (L / nbx) * 64;

    int wm = (wid & 1) * 32, wn = (wid >> 1) * 64;
    int fr = lane & 15, kq = lane >> 4;

    int srow = t >> 2, sslot = t & 3;
    int sko = ((sslot ^ ((srow >> 1) & 3)) << 3);

    f32x4 acc[2][4] = {};

    for (int k0 = 0; k0 < Ktot; k0 += 32) {
        {
            const short* sa = A + (size_t)(bm + srow) * lda + k0 + sko;
            short* da = As + (size_t)(wid << 6) * 8;
            __builtin_amdgcn_global_load_lds((const __attribute__((address_space(1))) void*)sa,
                                             (__attribute__((address_space(3))) void*)da, 16, 0, 0);
            #pragma unroll
            for (int qq = 0; qq < 2; qq++) {
                int v = qq * 256 + t;
                int rowb = v >> 2, slotb = v & 3;
                int skob = ((slotb ^ ((rowb >> 1) & 3)) << 3);
                const short* sb = B + (size_t)(bn + rowb) * ldb + k0 + skob;
                short* db = Bs + (size_t)(qq * 256 + (wid << 6)) * 8;
                __builtin_amdgcn_global_load_lds((const __attribute__((address_space(1))) void*)sb,
                                                 (__attribute__((address_space(3))) void*)db, 16, 0, 0);
            }
        }
        __syncthreads();
        bf16x8 af[2], bfv[4];
        #pragma unroll
        for (int i = 0; i < 2; i++) {
            int rowa = wm + i * 16 + fr;
            af[i] = *(const bf16x8*)(As + rowa * 32 + ((kq ^ ((rowa >> 1) & 3)) << 3));
        }
        #pragma unroll
        for (int j = 0; j < 4; j++) {
            int rowb = wn + j * 16 + fr;
            bfv[j] = *(const bf16x8*)(Bs + rowb * 32 + ((kq ^ ((rowb >> 1) & 3)) << 3));
        }
        #pragma unroll
        for (int i = 0; i < 2; i++)
            #pragma unroll
            for (int j = 0; j < 4; j++)
                acc[i][j] = __builtin_amdgcn_mfma_f32_16x16x32_bf16(af[i], bfv[j], acc[i][j], 0, 0, 0);
        __syncthreads();
    }
    // C write (bf16)
    #pragma unroll
    for (int i = 0; i < 2; i++) {
        int rbase = bm + wm + i * 16 + kq * 4;
        #pragma unroll
        for (int j = 0; j < 4; j++) {
            int colc = bn + wn + j * 16 + fr;
            #pragma unroll
            for (int rg = 0; rg < 4; rg++) {
                int rr = rbase + rg;
                if (rr < M) C[(size_t)rr * N + colc] = f2bf(acc[i][j][rg]);
            }
        }
    }
    // fused layer-1 scores: this block covers cols [bn, bn+128) = one full head
    float asv[4], adv[4];
    #pragma unroll
    for (int j = 0; j < 4; j++) {
        int colc = bn + wn + j * 16 + fr;
        asv[j] = a_src[colc];
        adv[j] = a_dst[colc];
    }
    float ps[8], pd[8];
    #pragma unroll
    for (int i = 0; i < 2; i++)
        #pragma unroll
        for (int rg = 0; rg < 4; rg++) {
            int k8 = i * 4 + rg;
            ps[k8] = acc[i][0][rg] * asv[0] + acc[i][1][rg] * asv[1]
                   + acc[i][2][rg] * asv[2] + acc[i][3][rg] * asv[3];
            pd[k8] = acc[i][0][rg] * adv[0] + acc[i][1][rg] * adv[1]
                   + acc[i][2][rg] * adv[2] + acc[i][3][rg] * adv[3];
        }
    #pragma unroll
    for (int k8 = 0; k8 < 8; k8++) {
        #pragma unroll
        for (int off = 1; off < 16; off <<= 1) {
            ps[k8] += __shfl_xor(ps[k8], off);
            pd[k8] += __shfl_xor(pd[k8], off);
        }
    }
    if (fr == 0) {
        #pragma unroll
        for (int i = 0; i < 2; i++)
            #pragma unroll
            for (int rg = 0; rg < 4; rg++) {
                int rl = wm + i * 16 + kq * 4 + rg;
                sred[wid][rl][0] = ps[i * 4 + rg];
                sred[wid][rl][1] = pd[i * 4 + rg];
            }
    }
    __syncthreads();
    if (wid < 2 && fr == 0) {
        int hh = bn >> 7;
        #pragma unroll
        for (int i = 0; i < 2; i++)
            #pragma unroll
            for (int rg = 0; rg < 4; rg++) {
                int rl = wm + i * 16 + kq * 4 + rg;
                int rr = bm + rl;
                if (rr < M) {
                    ssrc[rr * 8 + hh] = sred[wid][rl][0] + sred[wid + 2][rl][0];
                    sdst[rr * 8 + hh] = sred[wid][rl][1] + sred[wid + 2][rl][1];
                }
            }
    }
}

// ---------------- GEMM2: 64x64 tile, BK=32, fused layer-2 scores (one head/block) ----------------
__global__ __launch_bounds__(256) void k_mfma64(const short* __restrict__ A,
                                                const short* __restrict__ B,
                                                unsigned short* __restrict__ C,
                                                const float* __restrict__ a_src,
                                                const float* __restrict__ a_dst,
                                                float* __restrict__ ssrc,
                                                float* __restrict__ sdst,
                                                int M, int N, int Ktot,
                                                int lda, int ldb) {
    __shared__ short As[64 * 32];
    __shared__ short Bs[64 * 32];
    __shared__ float sred[4][64][2];
    int t = threadIdx.x;
    int lane = t & 63;
    int wid = t >> 6;

    int nbx = N >> 6;
    int nb = gridDim.x;
    int q = nb >> 3, r = nb & 7;
    int xcd = blockIdx.x & 7, pos = blockIdx.x >> 3;
    int L = (xcd < r ? xcd * (q + 1) : r * (q + 1) + (xcd - r) * q) + pos;
    int bn = (L % nbx) * 64;
    int bm = (L / nbx) * 64;

    int wm = (wid >> 1) * 32, wn = (wid & 1) * 32;
    int fr = lane & 15, kq = lane >> 4;

    int srow = t >> 2, sslot = t & 3;
    int sko = ((sslot ^ ((srow >> 1) & 3)) << 3);

    f32x4 acc[2][2] = {};

    for (int k0 = 0; k0 < Ktot; k0 += 32) {
        {
            const short* sa = A + (size_t)(bm + srow) * lda + k0 + sko;
            const short* sb = B + (size_t)(bn + srow) * ldb + k0 + sko;
            short* da = As + (size_t)(wid << 6) * 8;
            short* db = Bs + (size_t)(wid << 6) * 8;
            __builtin_amdgcn_global_load_lds((const __attribute__((address_space(1))) void*)sa,
                                             (__attribute__((address_space(3))) void*)da, 16, 0, 0);
            __builtin_amdgcn_global_load_lds((const __attribute__((address_space(1))) void*)sb,
                                             (__attribute__((address_space(3))) void*)db, 16, 0, 0);
        }
        __syncthreads();
        bf16x8 af[2], bfv[2];
        #pragma unroll
        for (int i = 0; i < 2; i++) {
            int rowa = wm + i * 16 + fr;
            int rowb = wn + i * 16 + fr;
            af[i]  = *(const bf16x8*)(As + rowa * 32 + ((kq ^ ((rowa >> 1) & 3)) << 3));
            bfv[i] = *(const bf16x8*)(Bs + rowb * 32 + ((kq ^ ((rowb >> 1) & 3)) << 3));
        }
        #pragma unroll
        for (int i = 0; i < 2; i++)
            #pragma unroll
            for (int j = 0; j < 2; j++)
                acc[i][j] = __builtin_amdgcn_mfma_f32_16x16x32_bf16(af[i], bfv[j], acc[i][j], 0, 0, 0);
        __syncthreads();
    }
    #pragma unroll
    for (int i = 0; i < 2; i++) {
        int rbase = bm + wm + i * 16 + kq * 4;
        #pragma unroll
        for (int j = 0; j < 2; j++) {
            int colc = bn + wn + j * 16 + fr;
            #pragma unroll
            for (int rg = 0; rg < 4; rg++) {
                int rr = rbase + rg;
                if (rr < M) C[(size_t)rr * N + colc] = f2bf(acc[i][j][rg]);
            }
        }
    }
    // fused scores (C=64: block = one head)
    float asv[2], adv[2];
    #pragma unroll
    for (int j = 0; j < 2; j++) {
        int colc = bn + wn + j * 16 + fr;
        asv[j] = a_src[colc];
        adv[j] = a_dst[colc];
    }
    float ps[8], pd[8];
    #pragma unroll
    for (int i = 0; i < 2; i++)
        #pragma unroll
        for (int rg = 0; rg < 4; rg++) {
            int k8 = i * 4 + rg;
            ps[k8] = acc[i][0][rg] * asv[0] + acc[i][1][rg] * asv[1];
            pd[k8] = acc[i][0][rg] * adv[0] + acc[i][1][rg] * adv[1];
        }
    #pragma unroll
    for (int k8 = 0; k8 < 8; k8++) {
        #pragma unroll
        for (int off = 1; off < 16; off <<= 1) {
            ps[k8] += __shfl_xor(ps[k8], off);
            pd[k8] += __shfl_xor(pd[k8], off);
        }
    }
    if (fr == 0) {
        #pragma unroll
        for (int i = 0; i < 2; i++)
            #pragma unroll
            for (int rg = 0; rg < 4; rg++) {
                int rl = wm + i * 16 + kq * 4 + rg;
                sred[wid][rl][0] = ps[i * 4 + rg];
                sred[wid][rl][1] = pd[i * 4 + rg];
            }
    }
    __syncthreads();
    if ((wid & 1) == 0 && fr == 0) {
        int hh = bn >> 6;
        #pragma unroll
        for (int i = 0; i < 2; i++)
            #pragma unroll
            for (int rg = 0; rg < 4; rg++) {
                int rl = wm + i * 16 + kq * 4 + rg;
                int rr = bm + rl;
                if (rr < M) {
                    ssrc[rr * 8 + hh] = sred[wid][rl][0] + sred[wid | 1][rl][0];
                    sdst[rr * 8 + hh] = sred[wid][rl][1] + sred[wid | 1][rl][1];
                }
            }
    }
}

// ---------------- layer-1 aggregation: wave per (node, 512-col slice) ----------------
template<int H, int C, int CB, bool ELU, bool BFOUT>
__global__ __launch_bounds__(256) void k_agg_wave(const unsigned short* __restrict__ hsrc,
                                                  const float* __restrict__ ssrc,
                                                  const float* __restrict__ sdst,
                                                  const int* __restrict__ col,
                                                  const int* __restrict__ row_off,
                                                  const float* __restrict__ bias,
                                                  float* __restrict__ out,
                                                  unsigned short* __restrict__ osp,
                                                  int nw) {
    constexpr int D = H * C;
    int lane = threadIdx.x & 63;
    int w = blockIdx.x * 4 + (threadIdx.x >> 6);
    if (w >= nw) return;
    int n, cb;
    if (CB == 2) { n = w >> 1; cb = w & 1; } else { n = w; cb = 0; }
    int col0 = cb * 512 + lane * 8;
    int myhead = col0 / C;
    float sd = sdst[n * H + myhead];
    int beg = row_off[n], end = row_off[n + 1];
    const unsigned short* hbase = hsrc + col0;

    float acc[8] = {0.f, 0.f, 0.f, 0.f, 0.f, 0.f, 0.f, 0.f};
    float den = 0.f;
    #pragma unroll 2
    for (int j = beg; j < end; j++) {
        int cj = col[j];
        float s = ssrc[cj * H + myhead] + sd;
        s = (s >= 0.f) ? s : NEG_SLOPE * s;
        float ex = __expf(s);
        den += ex;
        uint4 u = *(const uint4*)(hbase + (size_t)cj * D);
        acc[0] += ex * bflo(u.x); acc[1] += ex * bfhi(u.x);
        acc[2] += ex * bflo(u.y); acc[3] += ex * bfhi(u.y);
        acc[4] += ex * bflo(u.z); acc[5] += ex * bfhi(u.z);
        acc[6] += ex * bflo(u.w); acc[7] += ex * bfhi(u.w);
    }
    float iv = 1.f / (den + EPS_DEN);
    float vals[8];
    #pragma unroll
    for (int v = 0; v < 8; v++) {
        float val = acc[v] * iv + bias[col0 + v];
        if (ELU) val = (val > 0.f) ? val : (__expf(val) - 1.f);
        vals[v] = val;
    }
    if (BFOUT) {
        uint4 o;
        o.x = (unsigned)f2bf(vals[0]) | ((unsigned)f2bf(vals[1]) << 16);
        o.y = (unsigned)f2bf(vals[2]) | ((unsigned)f2bf(vals[3]) << 16);
        o.z = (unsigned)f2bf(vals[4]) | ((unsigned)f2bf(vals[5]) << 16);
        o.w = (unsigned)f2bf(vals[6]) | ((unsigned)f2bf(vals[7]) << 16);
        *(uint4*)(osp + (size_t)n * D + col0) = o;
    } else {
        *(f32x4*)(out + (size_t)n * D + col0) = *(f32x4*)&vals[0];
        *(f32x4*)(out + (size_t)n * D + col0 + 4) = *(f32x4*)&vals[4];
    }
}

// ---------------- layer-2 aggregation + ELU + W3-GEMM + layer-3 scores, wave per node ----------------
__global__ __launch_bounds__(256) void k_agg2_l3(const unsigned short* __restrict__ hsrc,
                                                 const float* __restrict__ ssrc,
                                                 const float* __restrict__ sdst,
                                                 const int* __restrict__ col,
                                                 const int* __restrict__ row_off,
                                                 const float* __restrict__ bias,
                                                 const float* __restrict__ W3,
                                                 const float* __restrict__ as3,
                                                 const float* __restrict__ ad3,
                                                 float* __restrict__ h3,
                                                 float* __restrict__ ssrc3,
                                                 float* __restrict__ sdst3,
                                                 int Nn) {
    constexpr int D = 512;
    int lane = threadIdx.x & 63;
    int n = blockIdx.x * 4 + (threadIdx.x >> 6);
    if (n >= Nn) return;
    int col0 = lane * 8;
    int myhead = lane >> 3;
    float sd = sdst[n * 8 + myhead];
    int beg = row_off[n], end = row_off[n + 1];
    const unsigned short* hbase = hsrc + col0;

    float acc[8] = {0.f, 0.f, 0.f, 0.f, 0.f, 0.f, 0.f, 0.f};
    float den = 0.f;
    #pragma unroll 2
    for (int j = beg; j < end; j++) {
        int cj = col[j];
        float s = ssrc[cj * 8 + myhead] + sd;
        s = (s >= 0.f) ? s : NEG_SLOPE * s;
        float ex = __expf(s);
        den += ex;
        uint4 u = *(const uint4*)(hbase + (size_t)cj * D);
        acc[0] += ex * bflo(u.x); acc[1] += ex * bfhi(u.x);
        acc[2] += ex * bflo(u.y); acc[3] += ex * bfhi(u.y);
        acc[4] += ex * bflo(u.z); acc[5] += ex * bfhi(u.z);
        acc[6] += ex * bflo(u.w); acc[7] += ex * bfhi(u.w);
    }
    float iv = 1.f / (den + EPS_DEN);
    float t0 = 0.f, t1 = 0.f, t2 = 0.f;
    #pragma unroll
    for (int v = 0; v < 8; v++) {
        float val = acc[v] * iv + bias[col0 + v];
        val = (val > 0.f) ? val : (__expf(val) - 1.f);
        const float* wp = W3 + (size_t)(col0 + v) * 3;
        t0 += val * wp[0];
        t1 += val * wp[1];
        t2 += val * wp[2];
    }
    #pragma unroll
    for (int off = 32; off >= 1; off >>= 1) {
        t0 += __shfl_xor(t0, off);
        t1 += __shfl_xor(t1, off);
        t2 += __shfl_xor(t2, off);
    }
    if (lane == 0) {
        h3[n * 3 + 0] = t0; h3[n * 3 + 1] = t1; h3[n * 3 + 2] = t2;
        ssrc3[n] = t0 * as3[0] + t1 * as3[1] + t2 * as3[2];
        sdst3[n] = t0 * ad3[0] + t1 * ad3[1] + t2 * ad3[2];
    }
}

// ---------------- fused layer-3: softmax + aggregation + log_softmax ----------------
__global__ void k_l3_fused(const float* __restrict__ h3, const float* __restrict__ ssrc,
                           const float* __restrict__ sdst, const int* __restrict__ col,
                           const int* __restrict__ row_off, const float* __restrict__ b3,
                           float* __restrict__ out, int Nn) {
    int n = blockIdx.x * blockDim.x + threadIdx.x;
    if (n >= Nn) return;
    int beg = row_off[n], end = row_off[n + 1];
    float sd = sdst[n];
    float den = 0.f, a0 = 0.f, a1 = 0.f, a2 = 0.f;
    for (int j = beg; j < end; j++) {
        int sI = col[j];
        float s = ssrc[sI] + sd;
        s = (s >= 0.f) ? s : NEG_SLOPE * s;
        float ex = __expf(s);
        den += ex;
        a0 += ex * h3[sI * 3 + 0];
        a1 += ex * h3[sI * 3 + 1];
        a2 += ex * h3[sI * 3 + 2];
    }
    float iv = 1.f / (den + EPS_DEN);
    float v0 = a0 * iv + b3[0], v1 = a1 * iv + b3[1], v2 = a2 * iv + b3[2];
    float m = fmaxf(v0, fmaxf(v1, v2));
    float l = logf(__expf(v0 - m) + __expf(v1 - m) + __expf(v2 - m));
    out[n * 3 + 0] = v0 - m - l;
    out[n * 3 + 1] = v1 - m - l;
    out[n * 3 + 2] = v2 - m - l;
}

extern "C" void kernel_launch(void* const* d_in, const int* in_sizes, int n_in,
                              void* d_out, int out_size, void* d_ws, size_t ws_size,
                              hipStream_t stream) {
    (void)n_in; (void)out_size; (void)ws_size;
    const float* x   = (const float*)d_in[0];
    const int*   ei  = (const int*)d_in[1];
    const float* W1  = (const float*)d_in[2];
    const float* as1 = (const float*)d_in[3];
    const float* ad1 = (const float*)d_in[4];
    const float* b1  = (const float*)d_in[5];
    const float* W2  = (const float*)d_in[6];
    const float* as2 = (const float*)d_in[7];
    const float* ad2 = (const float*)d_in[8];
    const float* b2  = (const float*)d_in[9];
    const float* W3  = (const float*)d_in[10];
    const float* as3 = (const float*)d_in[11];
    const float* ad3 = (const float*)d_in[12];
    const float* b3  = (const float*)d_in[13];
    float* out = (float*)d_out;

    const int Nn = in_sizes[0] / 64;   // 10000
    const int E  = in_sizes[1] / 2;    // 160000
    const int ET = E + Nn;
    const int Mp = ((Nn + 127) / 128) * 128;   // 10112

    char* ws = (char*)d_ws;
    size_t off = 0;
    auto alloc = [&](size_t bytes) -> void* {
        void* p = ws + off;
        off = (off + bytes + 255) & ~(size_t)255;
        return p;
    };
    unsigned short* hbuf = (unsigned short*)alloc((size_t)Mp * 1024 * 2);
    unsigned short* A2   = (unsigned short*)alloc((size_t)Mp * 1024 * 2);
    float* h3   = (float*)alloc((size_t)Nn * 3 * 4);
    short* A1   = (short*)alloc((size_t)Mp * 128 * 2);
    short* B1t  = (short*)alloc((size_t)1024 * 128 * 2);
    short* B2t  = (short*)alloc((size_t)512 * 1024 * 2);
    float* ssrc = (float*)alloc((size_t)Nn * 8 * 4);
    float* sdst = (float*)alloc((size_t)Nn * 8 * 4);
    float* ssrcB= (float*)alloc((size_t)Nn * 8 * 4);
    float* sdstB= (float*)alloc((size_t)Nn * 8 * 4);
    float* ssrc3= (float*)alloc((size_t)Nn * 4);
    float* sdst3= (float*)alloc((size_t)Nn * 4);
    int* counts = (int*)alloc((size_t)Nn * 2 * 4);
    int* cursor = counts + Nn;
    int* row_off= (int*)alloc((size_t)(Nn + 1) * 4);
    int* colb   = (int*)alloc((size_t)ET * 4);

    hipMemsetAsync(counts, 0, (size_t)Nn * 2 * 4, stream);

    int etb = (ET + 255) / 256;
    int xb = (Mp * 64 + 255) / 256;
    int preb = etb + xb + 64 + 512;
    k_pre<<<preb, 256, 0, stream>>>(ei, E, Nn, counts, x, A1, Mp, W1, B1t, W2, B2t);
    k_scan<<<1, 256, 0, stream>>>(counts, Nn, ET, row_off);
    k_scatter<<<etb, 256, 0, stream>>>(ei, E, Nn, row_off, cursor, colb);

    // ---- layer 1: 64 -> 8x128 concat (A split 2-term, scores fused) ----
    {
        int nb = (1024 / 128) * (Mp / 64);
        k_mfma_w<<<nb, 256, 0, stream>>>(A1, B1t, hbuf, as1, ad1, ssrc, sdst,
                                         Nn, 1024, 128, 128, 128);
        int nw = Nn * 2;
        k_agg_wave<8, 128, 2, true, true><<<(nw + 3) / 4, 256, 0, stream>>>(
            hbuf, ssrc, sdst, colb, row_off, b1, nullptr, A2, nw);
    }
    // ---- layer 2: 1024 -> 8x64 concat (plain bf16 GEMM, scores fused) ----
    {
        int nb = (512 / 64) * (Mp / 64);
        k_mfma64<<<nb, 256, 0, stream>>>((const short*)A2, B2t, hbuf, as2, ad2, ssrcB, sdstB,
                                         Nn, 512, 1024, 1024, 1024);
        k_agg2_l3<<<(Nn + 3) / 4, 256, 0, stream>>>(hbuf, ssrcB, sdstB, colb, row_off, b2,
                                                    W3, as3, ad3, h3, ssrc3, sdst3, Nn);
    }
    // ---- layer 3: segment softmax + aggregate + log_softmax ----
    k_l3_fused<<<(Nn + 255) / 256, 256, 0, stream>>>(h3, ssrc3, sdst3, colb, row_off, b3, out, Nn);
}